// Round 18
// baseline (93.075 us; speedup 1.0000x reference)
//
#include <hip/hip_runtime.h>
#include <math.h>

#define Lc 128
#define Rc 1024
#define Pc 8
#define Ec 64
#define Fc 64

// exp(-((d-mu)/sigma)^2) = exp2(-(C*(d-mu))^2), C = (1/0.15625)*sqrt(log2(e))
#define CSCALE   7.68718341623328f
#define MU_STEP  0.15873015873015873f   // 10/63
#define MUC      (MU_STEP * CSCALE)
#define SKIP_THR 6.5f                   // |tt|>6.5 -> g<2^-42: negligible

#define BM 32        // l per block
#define BN 32        // r per block
#define EC 8         // e per block
#define NBLKM ((Lc/BM)*(Rc/BN)*(Ec/EC))   // 4*32*8 = 1024

typedef __attribute__((ext_vector_type(8))) short short8;   // 8 bf16
typedef __attribute__((ext_vector_type(4))) float f32x4;

__device__ __forceinline__ unsigned short bf16_rn(float x) {
    unsigned int u = __float_as_uint(x);
    u += 0x7FFF + ((u >> 16) & 1);
    return (unsigned short)(u >> 16);
}
// pack hi-bf16 (TRUNCATED) of two f32
__device__ __forceinline__ unsigned int hipack(float x0, float x1) {
    return (__float_as_uint(x0) >> 16) | (__float_as_uint(x1) & 0xFFFF0000u);
}
// pack lo-bf16 (residual vs truncated hi) of two f32
__device__ __forceinline__ unsigned int lopack(float x0, float x1) {
    float r0 = x0 - __uint_as_float(__float_as_uint(x0) & 0xFFFF0000u);
    float r1 = x1 - __uint_as_float(__float_as_uint(x1) & 0xFFFF0000u);
    return ((unsigned int)bf16_rn(r1) << 16) | (unsigned int)bf16_rn(r0);
}

// ---- fused cvt+GEMM+fold+final-reduce (single kernel) ----
__global__ __launch_bounds__(256, 2)
void ff_mfma(const float* __restrict__ lig_feat,
             const float* __restrict__ rec_feat,
             const float* __restrict__ lig_coords,
             const float* __restrict__ rec_coords,
             float* __restrict__ partial,
             int* __restrict__ counter,
             float* __restrict__ out)
{
    __shared__ __align__(16) unsigned short stg[2][2][32][16][8];   // 32 KB
    __shared__ float lcs[Pc][96];    // coords slice; reused as last-block scratch
    __shared__ float rcs[96];
    __shared__ float wred[4][Pc];
    __shared__ int lastBlk;

    const int tid  = threadIdx.x;
    const int lane = tid & 63;
    const int w    = tid >> 6;
    const int n16  = lane & 15;
    const int kg   = lane >> 4;
    const int sr   = w >> 1;
    const int sc   = w & 1;

    const int bid = blockIdx.x;
    const int loc = bid >> 3;
    const int rt  = (bid & 7) * 4 + (loc & 3);
    const int lt  = (loc >> 2) & 3;
    const int ez  = loc >> 4;
    const int r0  = rt * BN;
    const int l0  = lt * BM;
    const int e0  = ez * EC;

    for (int i = tid; i < Pc * 96; i += 256) {
        int p = i / 96, q = i - p * 96;
        lcs[p][q] = lig_coords[p * (Lc * 3) + l0 * 3 + q];
    }
    if (tid < 96) rcs[tid] = rec_coords[r0 * 3 + tid];
    __syncthreads();

    // per-lane distances: l = sr*16 + kg*4 + reg, r = sc*16 + n16
    float dsc[Pc][4];
    {
        const int rb = (sc * 16 + n16) * 3;
        const float rx = rcs[rb], ry = rcs[rb + 1], rz = rcs[rb + 2];
        #pragma unroll
        for (int reg = 0; reg < 4; ++reg) {
            const int lb = (sr * 16 + kg * 4 + reg) * 3;
            #pragma unroll
            for (int p = 0; p < Pc; ++p) {
                float dx = lcs[p][lb]     - rx;
                float dy = lcs[p][lb + 1] - ry;
                float dz = lcs[p][lb + 2] - rz;
                dsc[p][reg] = sqrtf(dx * dx + dy * dy + dz * dz) * CSCALE;
            }
        }
    }

    // per-pose wave min/max of dsc -> SGPRs (for scalar skip decisions)
    unsigned sminb[Pc], smaxb[Pc];
    #pragma unroll
    for (int p = 0; p < Pc; ++p) {
        float mn = fminf(fminf(dsc[p][0], dsc[p][1]), fminf(dsc[p][2], dsc[p][3]));
        float mx = fmaxf(fmaxf(dsc[p][0], dsc[p][1]), fmaxf(dsc[p][2], dsc[p][3]));
        #pragma unroll
        for (int off = 32; off >= 1; off >>= 1) {
            mn = fminf(mn, __shfl_xor(mn, off, 64));
            mx = fmaxf(mx, __shfl_xor(mx, off, 64));
        }
        sminb[p] = __builtin_amdgcn_readfirstlane(__float_as_uint(mn));
        smaxb[p] = __builtin_amdgcn_readfirstlane(__float_as_uint(mx));
    }

    // staging roles
    const int half = tid >> 7;
    const int srow = (tid >> 2) & 31;
    const int fq   = tid & 3;
    const float* sbase = (half ? rec_feat + (size_t)(r0 + srow) * (Ec * Fc)
                               : lig_feat + (size_t)(l0 + srow) * (Ec * Fc)) + fq * 16;

    float4 pf[4];
    auto ld = [&](int e) {
        #pragma unroll
        for (int j = 0; j < 4; ++j)
            pf[j] = *(const float4*)(sbase + (size_t)e * Fc + j * 4);
    };
    auto cw = [&](int nb) {
        uint4 H0, H1, L0, L1;
        H0.x = hipack(pf[0].x, pf[0].y); H0.y = hipack(pf[0].z, pf[0].w);
        H0.z = hipack(pf[1].x, pf[1].y); H0.w = hipack(pf[1].z, pf[1].w);
        H1.x = hipack(pf[2].x, pf[2].y); H1.y = hipack(pf[2].z, pf[2].w);
        H1.z = hipack(pf[3].x, pf[3].y); H1.w = hipack(pf[3].z, pf[3].w);
        L0.x = lopack(pf[0].x, pf[0].y); L0.y = lopack(pf[0].z, pf[0].w);
        L0.z = lopack(pf[1].x, pf[1].y); L0.w = lopack(pf[1].z, pf[1].w);
        L1.x = lopack(pf[2].x, pf[2].y); L1.y = lopack(pf[2].z, pf[2].w);
        L1.z = lopack(pf[3].x, pf[3].y); L1.w = lopack(pf[3].z, pf[3].w);
        const int sm = srow & 15;
        *(uint4*)&stg[nb][half][srow][(fq * 2)         ^ sm][0] = H0;
        *(uint4*)&stg[nb][half][srow][(fq * 2 + 1)     ^ sm][0] = H1;
        *(uint4*)&stg[nb][half][srow][(8 + fq * 2)     ^ sm][0] = L0;
        *(uint4*)&stg[nb][half][srow][(8 + fq * 2 + 1) ^ sm][0] = L1;
    };

    ld(e0);
    cw(0);
    ld(e0 + 1);

    float us[Pc];
    #pragma unroll
    for (int p = 0; p < Pc; ++p) us[p] = 0.f;

    const int Arow = sr * 16 + n16;
    const int Brow = sc * 16 + n16;
#define RD(hf, rowv, slot) (*(const short8*)&stg[cur][hf][rowv][(slot) ^ ((rowv) & 15)][0])

    for (int t = 0; t < EC; ++t) {
        __syncthreads();
        const int cur = t & 1;
        const float musC = (float)(e0 + t) * MUC;

        // wave-uniform activity per pose (scalar branches; ~0 cost when skipped)
        bool act[Pc];
        bool any = false;
        #pragma unroll
        for (int p = 0; p < Pc; ++p) {
            const float mn = __uint_as_float(sminb[p]);
            const float mx = __uint_as_float(smaxb[p]);
            act[p] = (mn - musC <= SKIP_THR) && (mx - musC >= -SKIP_THR);
            any = any || act[p];
        }

        f32x4 acc = {0.f, 0.f, 0.f, 0.f};
        if (any) {
            short8 a0 = RD(0, Arow, kg);
            short8 b0 = RD(1, Brow, kg);
            acc = __builtin_amdgcn_mfma_f32_16x16x32_bf16(a0, b0, acc, 0, 0, 0);
            short8 a1 = RD(0, Arow, 8 + kg);
            acc = __builtin_amdgcn_mfma_f32_16x16x32_bf16(a1, b0, acc, 0, 0, 0);
            short8 b1 = RD(1, Brow, 8 + kg);
            acc = __builtin_amdgcn_mfma_f32_16x16x32_bf16(a0, b1, acc, 0, 0, 0);
            a0 = RD(0, Arow, 4 + kg);
            b0 = RD(1, Brow, 4 + kg);
            acc = __builtin_amdgcn_mfma_f32_16x16x32_bf16(a0, b0, acc, 0, 0, 0);
            a1 = RD(0, Arow, 12 + kg);
            acc = __builtin_amdgcn_mfma_f32_16x16x32_bf16(a1, b0, acc, 0, 0, 0);
            b1 = RD(1, Brow, 12 + kg);
            acc = __builtin_amdgcn_mfma_f32_16x16x32_bf16(a0, b1, acc, 0, 0, 0);

            #pragma unroll
            for (int p = 0; p < Pc; ++p) {
                if (act[p]) {
                    #pragma unroll
                    for (int reg = 0; reg < 4; ++reg) {
                        const float tt = dsc[p][reg] - musC;
                        us[p] = fmaf(acc[reg], __builtin_amdgcn_exp2f(-tt * tt), us[p]);
                    }
                }
            }
        }

        if (t + 1 < EC) cw((t + 1) & 1);
        if (t + 2 < EC) ld(e0 + t + 2);
    }
#undef RD

    // butterfly over 64 lanes, then across the 4 waves
    #pragma unroll
    for (int p = 0; p < Pc; ++p) {
        float v = us[p];
        #pragma unroll
        for (int off = 32; off >= 1; off >>= 1)
            v += __shfl_xor(v, off, 64);
        us[p] = v;
    }
    if (lane == 0) {
        #pragma unroll
        for (int p = 0; p < Pc; ++p) wred[w][p] = us[p];
    }
    __syncthreads();
    if (tid < Pc) {
        float s = 0.f;
        #pragma unroll
        for (int k = 0; k < 4; ++k) s += wred[k][tid];
        partial[(size_t)bid * Pc + tid] = s;
    }

    // ---- last-block final reduce (replaces the ff_reduce kernel) ----
    __threadfence();                       // release partial writes (device scope)
    if (tid == 0)
        lastBlk = (atomicAdd(counter, 1) == NBLKM - 1);
    __syncthreads();
    if (lastBlk) {
        __threadfence();                   // acquire all partials
        float v = 0.f;
        #pragma unroll
        for (int j = 0; j < NBLKM * Pc / 256; ++j)   // 32 coalesced loads
            v += partial[tid + 256 * j];
        float* red2 = &lcs[0][0];          // 256-float scratch (coords dead)
        red2[tid] = v;
        __syncthreads();
        if (tid < Pc) {
            float s = 0.f;
            #pragma unroll
            for (int k = 0; k < 32; ++k) s += red2[k * Pc + tid];
            out[tid] = 0.1f * s;
        }
    }
}

extern "C" void kernel_launch(void* const* d_in, const int* in_sizes, int n_in,
                              void* d_out, int out_size, void* d_ws, size_t ws_size,
                              hipStream_t stream)
{
    const float* lig_feat   = (const float*)d_in[0];
    const float* rec_feat   = (const float*)d_in[1];
    const float* lig_coords = (const float*)d_in[2];
    const float* rec_coords = (const float*)d_in[3];
    float* out     = (float*)d_out;
    float* partial = (float*)d_ws;                       // 32 KB
    int*   counter = (int*)((char*)d_ws + 32768);

    hipMemsetAsync(counter, 0, sizeof(int), stream);     // capture-safe, deterministic
    ff_mfma<<<NBLKM, 256, 0, stream>>>(lig_feat, rec_feat, lig_coords, rec_coords,
                                       partial, counter, out);
}

// Round 19
// 88.822 us; speedup vs baseline: 1.0479x; 1.0479x over previous
//
#include <hip/hip_runtime.h>
#include <math.h>

#define Lc 128
#define Rc 1024
#define Pc 8
#define Ec 64
#define Fc 64

// exp(-((d-mu)/sigma)^2) = exp2(-(C*(d-mu))^2), C = (1/0.15625)*sqrt(log2(e))
#define CSCALE   7.68718341623328f
#define MU_STEP  0.15873015873015873f   // 10/63
#define MUC      (MU_STEP * CSCALE)

#define BM 32        // l per block
#define BN 32        // r per block
#define EC 8         // e per block
#define NBLKM ((Lc/BM)*(Rc/BN)*(Ec/EC))   // 4*32*8 = 1024

typedef __attribute__((ext_vector_type(8))) short short8;   // 8 bf16
typedef __attribute__((ext_vector_type(4))) float f32x4;

__device__ __forceinline__ unsigned short bf16_rn(float x) {
    unsigned int u = __float_as_uint(x);
    u += 0x7FFF + ((u >> 16) & 1);
    return (unsigned short)(u >> 16);
}
// pack hi-bf16 (TRUNCATED) of two f32
__device__ __forceinline__ unsigned int hipack(float x0, float x1) {
    return (__float_as_uint(x0) >> 16) | (__float_as_uint(x1) & 0xFFFF0000u);
}
// pack lo-bf16 (residual vs truncated hi) of two f32
__device__ __forceinline__ unsigned int lopack(float x0, float x1) {
    float r0 = x0 - __uint_as_float(__float_as_uint(x0) & 0xFFFF0000u);
    float r1 = x1 - __uint_as_float(__float_as_uint(x1) & 0xFFFF0000u);
    return ((unsigned int)bf16_rn(r1) << 16) | (unsigned int)bf16_rn(r0);
}

// ---- fused cvt+GEMM+fold (R17 core, verbatim) + last-block final reduce ----
__global__ __launch_bounds__(256, 2)
void ff_mfma(const float* __restrict__ lig_feat,
             const float* __restrict__ rec_feat,
             const float* __restrict__ lig_coords,
             const float* __restrict__ rec_coords,
             float* __restrict__ partial,
             int* __restrict__ counter,
             float* __restrict__ out)
{
    __shared__ __align__(16) unsigned short stg[2][2][32][16][8];   // 32 KB
    __shared__ float lcs[Pc][96];    // coords slice; reused as last-block scratch
    __shared__ float rcs[96];
    __shared__ float wred[4][Pc];
    __shared__ int lastBlk;

    const int tid  = threadIdx.x;
    const int lane = tid & 63;
    const int w    = tid >> 6;
    const int n16  = lane & 15;
    const int kg   = lane >> 4;
    const int sr   = w >> 1;            // subtile row (l)
    const int sc   = w & 1;             // subtile col (r)

    // grid decode; bid&7 = XCD: each XCD owns 4 r-tiles (rec slice L2-resident)
    const int bid = blockIdx.x;
    const int loc = bid >> 3;                   // 0..127
    const int rt  = (bid & 7) * 4 + (loc & 3);  // 0..31
    const int lt  = (loc >> 2) & 3;             // 0..3
    const int ez  = loc >> 4;                   // 0..7
    const int r0  = rt * BN;
    const int l0  = lt * BM;
    const int e0  = ez * EC;

    // coords -> LDS
    for (int i = tid; i < Pc * 96; i += 256) {
        int p = i / 96, q = i - p * 96;
        lcs[p][q] = lig_coords[p * (Lc * 3) + l0 * 3 + q];
    }
    if (tid < 96) rcs[tid] = rec_coords[r0 * 3 + tid];
    __syncthreads();

    // per-lane distances: l = sr*16 + kg*4 + reg, r = sc*16 + n16
    float dsc[Pc][4];
    {
        const int rb = (sc * 16 + n16) * 3;
        const float rx = rcs[rb], ry = rcs[rb + 1], rz = rcs[rb + 2];
        #pragma unroll
        for (int reg = 0; reg < 4; ++reg) {
            const int lb = (sr * 16 + kg * 4 + reg) * 3;
            #pragma unroll
            for (int p = 0; p < Pc; ++p) {
                float dx = lcs[p][lb]     - rx;
                float dy = lcs[p][lb + 1] - ry;
                float dz = lcs[p][lb + 2] - rz;
                dsc[p][reg] = sqrtf(dx * dx + dy * dy + dz * dz) * CSCALE;
            }
        }
    }

    // staging roles: half = A/B, srow = row, fq = f-quarter (16 f32 = 64 B/thread)
    const int half = tid >> 7;
    const int srow = (tid >> 2) & 31;
    const int fq   = tid & 3;
    const float* sbase = (half ? rec_feat + (size_t)(r0 + srow) * (Ec * Fc)
                               : lig_feat + (size_t)(l0 + srow) * (Ec * Fc)) + fq * 16;

    float4 pf[4];
    auto ld = [&](int e) {
        #pragma unroll
        for (int j = 0; j < 4; ++j)
            pf[j] = *(const float4*)(sbase + (size_t)e * Fc + j * 4);
    };
    auto cw = [&](int nb) {   // convert pf -> split bf16, write 4 swizzled slots
        uint4 H0, H1, L0, L1;
        H0.x = hipack(pf[0].x, pf[0].y); H0.y = hipack(pf[0].z, pf[0].w);
        H0.z = hipack(pf[1].x, pf[1].y); H0.w = hipack(pf[1].z, pf[1].w);
        H1.x = hipack(pf[2].x, pf[2].y); H1.y = hipack(pf[2].z, pf[2].w);
        H1.z = hipack(pf[3].x, pf[3].y); H1.w = hipack(pf[3].z, pf[3].w);
        L0.x = lopack(pf[0].x, pf[0].y); L0.y = lopack(pf[0].z, pf[0].w);
        L0.z = lopack(pf[1].x, pf[1].y); L0.w = lopack(pf[1].z, pf[1].w);
        L1.x = lopack(pf[2].x, pf[2].y); L1.y = lopack(pf[2].z, pf[2].w);
        L1.z = lopack(pf[3].x, pf[3].y); L1.w = lopack(pf[3].z, pf[3].w);
        const int sm = srow & 15;
        *(uint4*)&stg[nb][half][srow][(fq * 2)         ^ sm][0] = H0;
        *(uint4*)&stg[nb][half][srow][(fq * 2 + 1)     ^ sm][0] = H1;
        *(uint4*)&stg[nb][half][srow][(8 + fq * 2)     ^ sm][0] = L0;
        *(uint4*)&stg[nb][half][srow][(8 + fq * 2 + 1) ^ sm][0] = L1;
    };

    // prologue: stage e0 into buf 0; issue loads for e0+1
    ld(e0);
    cw(0);
    ld(e0 + 1);

    float us[Pc];
    #pragma unroll
    for (int p = 0; p < Pc; ++p) us[p] = 0.f;

    const int Arow = sr * 16 + n16;
    const int Brow = sc * 16 + n16;
#define RD(hf, rowv, slot) (*(const short8*)&stg[cur][hf][rowv][(slot) ^ ((rowv) & 15)][0])

    for (int t = 0; t < EC; ++t) {
        __syncthreads();                 // buf[t&1] visible; prev reads of buf[(t+1)&1] done
        const int cur = t & 1;

        // 6 split-MFMAs (hh + lh + hl; ll dropped, ~2^-16 rel)
        f32x4 acc = {0.f, 0.f, 0.f, 0.f};
        {
            short8 a0 = RD(0, Arow, kg);            // Ah0
            short8 b0 = RD(1, Brow, kg);            // Bh0
            acc = __builtin_amdgcn_mfma_f32_16x16x32_bf16(a0, b0, acc, 0, 0, 0);
            short8 a1 = RD(0, Arow, 8 + kg);        // Al0
            acc = __builtin_amdgcn_mfma_f32_16x16x32_bf16(a1, b0, acc, 0, 0, 0);
            short8 b1 = RD(1, Brow, 8 + kg);        // Bl0
            acc = __builtin_amdgcn_mfma_f32_16x16x32_bf16(a0, b1, acc, 0, 0, 0);
            a0 = RD(0, Arow, 4 + kg);               // Ah1
            b0 = RD(1, Brow, 4 + kg);               // Bh1
            acc = __builtin_amdgcn_mfma_f32_16x16x32_bf16(a0, b0, acc, 0, 0, 0);
            a1 = RD(0, Arow, 12 + kg);              // Al1
            acc = __builtin_amdgcn_mfma_f32_16x16x32_bf16(a1, b0, acc, 0, 0, 0);
            b1 = RD(1, Brow, 12 + kg);              // Bl1
            acc = __builtin_amdgcn_mfma_f32_16x16x32_bf16(a0, b1, acc, 0, 0, 0);
        }

        // fold atn into pose accumulators (straight-line, no branches)
        const float musC = (float)(e0 + t) * MUC;
        #pragma unroll
        for (int reg = 0; reg < 4; ++reg) {
            const float av = acc[reg];
            #pragma unroll
            for (int p = 0; p < Pc; ++p) {
                const float tt = dsc[p][reg] - musC;
                us[p] = fmaf(av, __builtin_amdgcn_exp2f(-tt * tt), us[p]);
            }
        }

        // convert + write next slice (loads issued a full step ago); then issue t+2
        if (t + 1 < EC) cw((t + 1) & 1);
        if (t + 2 < EC) ld(e0 + t + 2);
    }
#undef RD

    // butterfly over 64 lanes, then across the 4 waves
    #pragma unroll
    for (int p = 0; p < Pc; ++p) {
        float v = us[p];
        #pragma unroll
        for (int off = 32; off >= 1; off >>= 1)
            v += __shfl_xor(v, off, 64);
        us[p] = v;
    }
    if (lane == 0) {
        #pragma unroll
        for (int p = 0; p < Pc; ++p) wred[w][p] = us[p];
    }
    __syncthreads();
    if (tid < Pc) {
        float s = 0.f;
        #pragma unroll
        for (int k = 0; k < 4; ++k) s += wred[k][tid];
        partial[(size_t)bid * Pc + tid] = s;
    }

    // ---- last-block final reduce (replaces the ff_reduce kernel) ----
    __threadfence();                       // release partial writes (device scope)
    if (tid == 0)
        lastBlk = (atomicAdd(counter, 1) == NBLKM - 1);
    __syncthreads();
    if (lastBlk) {
        __threadfence();                   // acquire all partials
        float v = 0.f;
        #pragma unroll
        for (int j = 0; j < NBLKM * Pc / 256; ++j)   // 32 coalesced loads
            v += partial[tid + 256 * j];
        float* red2 = &lcs[0][0];          // 256-float scratch (coords dead)
        red2[tid] = v;
        __syncthreads();
        if (tid < Pc) {
            float s = 0.f;
            #pragma unroll
            for (int k = 0; k < 32; ++k) s += red2[k * Pc + tid];
            out[tid] = 0.1f * s;
        }
    }
}

extern "C" void kernel_launch(void* const* d_in, const int* in_sizes, int n_in,
                              void* d_out, int out_size, void* d_ws, size_t ws_size,
                              hipStream_t stream)
{
    const float* lig_feat   = (const float*)d_in[0];
    const float* rec_feat   = (const float*)d_in[1];
    const float* lig_coords = (const float*)d_in[2];
    const float* rec_coords = (const float*)d_in[3];
    float* out     = (float*)d_out;
    float* partial = (float*)d_ws;                       // 32 KB
    int*   counter = (int*)((char*)d_ws + 32768);

    hipMemsetAsync(counter, 0, sizeof(int), stream);     // capture-safe, deterministic
    ff_mfma<<<NBLKM, 256, 0, stream>>>(lig_feat, rec_feat, lig_coords, rec_coords,
                                       partial, counter, out);
}

// Round 20
// 48.359 us; speedup vs baseline: 1.9246x; 1.8367x over previous
//
#include <hip/hip_runtime.h>
#include <math.h>

#define Lc 128
#define Rc 1024
#define Pc 8
#define Ec 64
#define Fc 64

// exp(-((d-mu)/sigma)^2) = exp2(-(C*(d-mu))^2), C = (1/0.15625)*sqrt(log2(e))
#define CSCALE   7.68718341623328f
#define MU_STEP  0.15873015873015873f   // 10/63
#define MUC      (MU_STEP * CSCALE)

#define BM 32        // l per block
#define BN 32        // r per block
#define EC 8         // e per block
#define NBLKM ((Lc/BM)*(Rc/BN)*(Ec/EC))   // 4*32*8 = 1024

typedef __attribute__((ext_vector_type(8))) short short8;   // 8 bf16
typedef __attribute__((ext_vector_type(4))) float f32x4;

__device__ __forceinline__ unsigned short bf16_rn(float x) {
    unsigned int u = __float_as_uint(x);
    u += 0x7FFF + ((u >> 16) & 1);
    return (unsigned short)(u >> 16);
}
// pack hi-bf16 (TRUNCATED) of two f32
__device__ __forceinline__ unsigned int hipack(float x0, float x1) {
    return (__float_as_uint(x0) >> 16) | (__float_as_uint(x1) & 0xFFFF0000u);
}
// pack lo-bf16 (residual vs truncated hi) of two f32
__device__ __forceinline__ unsigned int lopack(float x0, float x1) {
    float r0 = x0 - __uint_as_float(__float_as_uint(x0) & 0xFFFF0000u);
    float r1 = x1 - __uint_as_float(__float_as_uint(x1) & 0xFFFF0000u);
    return ((unsigned int)bf16_rn(r1) << 16) | (unsigned int)bf16_rn(r0);
}

// ---- fused cvt+GEMM+fold, WAVE-PRIVATE staging: zero barriers in the K-loop ----
// Each wave owns a 16l x 16r subtile and stages its own A/B rows into a private
// 8 KB LDS slice (single-buffered: same-wave LDS ops are in program order, and
// the may-aliasing write-after-read forces the compiler to keep RDs before cw).
// No __syncthreads in the loop -> no vmcnt(0) drain -> prefetch stays in flight.
__global__ __launch_bounds__(256, 2)
void ff_mfma(const float* __restrict__ lig_feat,
             const float* __restrict__ rec_feat,
             const float* __restrict__ lig_coords,
             const float* __restrict__ rec_coords,
             float* __restrict__ partial)
{
    __shared__ __align__(16) unsigned short stg[4][2][16][16][8];   // 32 KB, per-wave slices
    __shared__ float lcs[Pc][96];
    __shared__ float rcs[96];
    __shared__ float wred[4][Pc];

    const int tid  = threadIdx.x;
    const int lane = tid & 63;
    const int w    = tid >> 6;
    const int n16  = lane & 15;
    const int kg   = lane >> 4;
    const int sr   = w >> 1;            // subtile row (l)
    const int sc   = w & 1;             // subtile col (r)

    // grid decode; bid&7 = XCD: each XCD owns 4 r-tiles (rec slice L2-resident)
    const int bid = blockIdx.x;
    const int loc = bid >> 3;                   // 0..127
    const int rt  = (bid & 7) * 4 + (loc & 3);  // 0..31
    const int lt  = (loc >> 2) & 3;             // 0..3
    const int ez  = loc >> 4;                   // 0..7
    const int r0  = rt * BN;
    const int l0  = lt * BM;
    const int e0  = ez * EC;

    // coords -> LDS
    for (int i = tid; i < Pc * 96; i += 256) {
        int p = i / 96, q = i - p * 96;
        lcs[p][q] = lig_coords[p * (Lc * 3) + l0 * 3 + q];
    }
    if (tid < 96) rcs[tid] = rec_coords[r0 * 3 + tid];
    __syncthreads();

    // per-lane distances: l = sr*16 + kg*4 + reg, r = sc*16 + n16
    float dsc[Pc][4];
    {
        const int rb = (sc * 16 + n16) * 3;
        const float rx = rcs[rb], ry = rcs[rb + 1], rz = rcs[rb + 2];
        #pragma unroll
        for (int reg = 0; reg < 4; ++reg) {
            const int lb = (sr * 16 + kg * 4 + reg) * 3;
            #pragma unroll
            for (int p = 0; p < Pc; ++p) {
                float dx = lcs[p][lb]     - rx;
                float dy = lcs[p][lb + 1] - ry;
                float dz = lcs[p][lb + 2] - rz;
                dsc[p][reg] = sqrtf(dx * dx + dy * dy + dz * dz) * CSCALE;
            }
        }
    }

    // wave-private staging roles: 32 lanes A (lig), 32 lanes B (rec);
    // row = (lane>>1)&15 within the wave's 16-row tile; fq = lane&1 covers
    // floats [fq*32, fq*32+32) of the row -> 8 float4 = 128 B per lane per e.
    const int half = lane >> 5;
    const int srow = (lane >> 1) & 15;
    const int fq   = lane & 1;
    const int grow = half ? (r0 + sc * 16 + srow) : (l0 + sr * 16 + srow);
    const float* sbase = (half ? rec_feat : lig_feat)
                         + (size_t)grow * (Ec * Fc) + fq * 32;

    float4 pf[8];
    auto ld = [&](int e) {
        #pragma unroll
        for (int j = 0; j < 8; ++j)
            pf[j] = *(const float4*)(sbase + (size_t)e * Fc + j * 4);
    };
    auto cw = [&]() {   // convert pf -> split bf16, write 8 swizzled slots (own slice)
        #pragma unroll
        for (int k = 0; k < 4; ++k) {
            uint4 H, L;
            H.x = hipack(pf[2 * k].x,     pf[2 * k].y);
            H.y = hipack(pf[2 * k].z,     pf[2 * k].w);
            H.z = hipack(pf[2 * k + 1].x, pf[2 * k + 1].y);
            H.w = hipack(pf[2 * k + 1].z, pf[2 * k + 1].w);
            L.x = lopack(pf[2 * k].x,     pf[2 * k].y);
            L.y = lopack(pf[2 * k].z,     pf[2 * k].w);
            L.z = lopack(pf[2 * k + 1].x, pf[2 * k + 1].y);
            L.w = lopack(pf[2 * k + 1].z, pf[2 * k + 1].w);
            *(uint4*)&stg[w][half][srow][(fq * 4 + k) ^ srow][0]       = H;
            *(uint4*)&stg[w][half][srow][((8 + fq * 4 + k)) ^ srow][0] = L;
        }
    };

    // prologue: stage e0; issue loads for e0+1
    ld(e0);
    cw();
    ld(e0 + 1);

    float us[Pc];
    #pragma unroll
    for (int p = 0; p < Pc; ++p) us[p] = 0.f;

#define RD(hf, slot) (*(const short8*)&stg[w][hf][n16][(slot) ^ n16][0])

    for (int t = 0; t < EC; ++t) {
        // 6 split-MFMAs (hh + lh + hl; ll dropped, ~2^-16 rel)
        f32x4 acc = {0.f, 0.f, 0.f, 0.f};
        {
            short8 a0 = RD(0, kg);            // Ah0
            short8 b0 = RD(1, kg);            // Bh0
            acc = __builtin_amdgcn_mfma_f32_16x16x32_bf16(a0, b0, acc, 0, 0, 0);
            short8 a1 = RD(0, 8 + kg);        // Al0
            acc = __builtin_amdgcn_mfma_f32_16x16x32_bf16(a1, b0, acc, 0, 0, 0);
            short8 b1 = RD(1, 8 + kg);        // Bl0
            acc = __builtin_amdgcn_mfma_f32_16x16x32_bf16(a0, b1, acc, 0, 0, 0);
            a0 = RD(0, 4 + kg);               // Ah1
            b0 = RD(1, 4 + kg);               // Bh1
            acc = __builtin_amdgcn_mfma_f32_16x16x32_bf16(a0, b0, acc, 0, 0, 0);
            a1 = RD(0, 12 + kg);              // Al1
            acc = __builtin_amdgcn_mfma_f32_16x16x32_bf16(a1, b0, acc, 0, 0, 0);
            b1 = RD(1, 12 + kg);              // Bl1
            acc = __builtin_amdgcn_mfma_f32_16x16x32_bf16(a0, b1, acc, 0, 0, 0);
        }

        // write next e (pf loaded a full iteration ago); program order keeps
        // these ds_writes after the 12 RDs above (may-alias). Then refill pf.
        if (t + 1 < EC) cw();
        if (t + 2 < EC) ld(e0 + t + 2);

        // fold atn into pose accumulators (overlaps MFMA/LDS latency)
        const float musC = (float)(e0 + t) * MUC;
        #pragma unroll
        for (int reg = 0; reg < 4; ++reg) {
            const float av = acc[reg];
            #pragma unroll
            for (int p = 0; p < Pc; ++p) {
                const float tt = dsc[p][reg] - musC;
                us[p] = fmaf(av, __builtin_amdgcn_exp2f(-tt * tt), us[p]);
            }
        }
    }
#undef RD

    // butterfly over 64 lanes, then across the 4 waves
    #pragma unroll
    for (int p = 0; p < Pc; ++p) {
        float v = us[p];
        #pragma unroll
        for (int off = 32; off >= 1; off >>= 1)
            v += __shfl_xor(v, off, 64);
        us[p] = v;
    }
    if (lane == 0) {
        #pragma unroll
        for (int p = 0; p < Pc; ++p) wred[w][p] = us[p];
    }
    __syncthreads();
    if (tid < Pc) {
        float s = 0.f;
        #pragma unroll
        for (int k = 0; k < 4; ++k) s += wred[k][tid];
        partial[(size_t)bid * Pc + tid] = s;
    }
}

// reduce NBLKM block-partials x 8 poses -> 8 outputs
__global__ void ff_reduce(const float* __restrict__ partial, float* __restrict__ out)
{
    const int w    = threadIdx.x >> 6;
    const int lane = threadIdx.x & 63;
    float v = 0.f;
    #pragma unroll
    for (int j = 0; j < NBLKM / 64; ++j)
        v += partial[(size_t)(lane + 64 * j) * Pc + w];
    #pragma unroll
    for (int off = 32; off >= 1; off >>= 1)
        v += __shfl_xor(v, off, 64);
    if (lane == 0) out[w] = 0.1f * v;
}

extern "C" void kernel_launch(void* const* d_in, const int* in_sizes, int n_in,
                              void* d_out, int out_size, void* d_ws, size_t ws_size,
                              hipStream_t stream)
{
    const float* lig_feat   = (const float*)d_in[0];
    const float* rec_feat   = (const float*)d_in[1];
    const float* lig_coords = (const float*)d_in[2];
    const float* rec_coords = (const float*)d_in[3];
    float* out     = (float*)d_out;
    float* partial = (float*)d_ws;   // 1024*8*4 = 32 KB

    ff_mfma<<<NBLKM, 256, 0, stream>>>(lig_feat, rec_feat, lig_coords, rec_coords, partial);
    ff_reduce<<<1, 512, 0, stream>>>(partial, out);
}

// Round 21
// 34.125 us; speedup vs baseline: 2.7275x; 1.4171x over previous
//
#include <hip/hip_runtime.h>
#include <math.h>

#define Lc 128
#define Rc 1024
#define Pc 8
#define Ec 64
#define Fc 64

// exp(-((d-mu)/sigma)^2) = exp2(-(C*(d-mu))^2), C = (1/0.15625)*sqrt(log2(e))
#define CSCALE   7.68718341623328f
#define MU_STEP  0.15873015873015873f   // 10/63
#define MUC      (MU_STEP * CSCALE)

#define BM 32        // l per block
#define BN 32        // r per block
#define EC 8         // e per block
#define NBLKM ((Lc/BM)*(Rc/BN)*(Ec/EC))   // 4*32*8 = 1024

typedef __attribute__((ext_vector_type(8))) short short8;   // 8 bf16
typedef __attribute__((ext_vector_type(4))) float f32x4;

__device__ __forceinline__ unsigned short bf16_rn(float x) {
    unsigned int u = __float_as_uint(x);
    u += 0x7FFF + ((u >> 16) & 1);
    return (unsigned short)(u >> 16);
}
// pack hi-bf16 (TRUNCATED) of two f32
__device__ __forceinline__ unsigned int hipack(float x0, float x1) {
    return (__float_as_uint(x0) >> 16) | (__float_as_uint(x1) & 0xFFFF0000u);
}
// pack lo-bf16 (residual vs truncated hi) of two f32
__device__ __forceinline__ unsigned int lopack(float x0, float x1) {
    float r0 = x0 - __uint_as_float(__float_as_uint(x0) & 0xFFFF0000u);
    float r1 = x1 - __uint_as_float(__float_as_uint(x1) & 0xFFFF0000u);
    return ((unsigned int)bf16_rn(r1) << 16) | (unsigned int)bf16_rn(r0);
}

// ---- fused cvt+GEMM+fold (R17 core) with raw-barrier pipeline: prefetch
// loads cross the barrier IN FLIGHT (no vmcnt(0) drain from __syncthreads).
__global__ __launch_bounds__(256, 2)
void ff_mfma(const float* __restrict__ lig_feat,
             const float* __restrict__ rec_feat,
             const float* __restrict__ lig_coords,
             const float* __restrict__ rec_coords,
             float* __restrict__ partial)
{
    __shared__ __align__(16) unsigned short stg[2][2][32][16][8];   // 32 KB
    __shared__ float lcs[Pc][96];
    __shared__ float rcs[96];
    __shared__ float wred[4][Pc];

    const int tid  = threadIdx.x;
    const int lane = tid & 63;
    const int w    = tid >> 6;
    const int n16  = lane & 15;
    const int kg   = lane >> 4;
    const int sr   = w >> 1;            // subtile row (l)
    const int sc   = w & 1;             // subtile col (r)

    // grid decode; bid&7 = XCD: each XCD owns 4 r-tiles (rec slice L2-resident)
    const int bid = blockIdx.x;
    const int loc = bid >> 3;                   // 0..127
    const int rt  = (bid & 7) * 4 + (loc & 3);  // 0..31
    const int lt  = (loc >> 2) & 3;             // 0..3
    const int ez  = loc >> 4;                   // 0..7
    const int r0  = rt * BN;
    const int l0  = lt * BM;
    const int e0  = ez * EC;

    // coords -> LDS
    for (int i = tid; i < Pc * 96; i += 256) {
        int p = i / 96, q = i - p * 96;
        lcs[p][q] = lig_coords[p * (Lc * 3) + l0 * 3 + q];
    }
    if (tid < 96) rcs[tid] = rec_coords[r0 * 3 + tid];
    __syncthreads();

    // per-lane distances: l = sr*16 + kg*4 + reg, r = sc*16 + n16
    float dsc[Pc][4];
    {
        const int rb = (sc * 16 + n16) * 3;
        const float rx = rcs[rb], ry = rcs[rb + 1], rz = rcs[rb + 2];
        #pragma unroll
        for (int reg = 0; reg < 4; ++reg) {
            const int lb = (sr * 16 + kg * 4 + reg) * 3;
            #pragma unroll
            for (int p = 0; p < Pc; ++p) {
                float dx = lcs[p][lb]     - rx;
                float dy = lcs[p][lb + 1] - ry;
                float dz = lcs[p][lb + 2] - rz;
                dsc[p][reg] = sqrtf(dx * dx + dy * dy + dz * dz) * CSCALE;
            }
        }
    }

    // staging roles: half = A/B, srow = row, fq = f-quarter (16 f32 = 64 B/thread)
    const int half = tid >> 7;
    const int srow = (tid >> 2) & 31;
    const int fq   = tid & 3;
    const float* sbase = (half ? rec_feat + (size_t)(r0 + srow) * (Ec * Fc)
                               : lig_feat + (size_t)(l0 + srow) * (Ec * Fc)) + fq * 16;

    float4 pf[4];
    auto ld = [&](int e) {
        #pragma unroll
        for (int j = 0; j < 4; ++j)
            pf[j] = *(const float4*)(sbase + (size_t)e * Fc + j * 4);
    };
    auto cw = [&](int nb) {   // convert pf -> split bf16, write 4 swizzled slots
        uint4 H0, H1, L0, L1;
        H0.x = hipack(pf[0].x, pf[0].y); H0.y = hipack(pf[0].z, pf[0].w);
        H0.z = hipack(pf[1].x, pf[1].y); H0.w = hipack(pf[1].z, pf[1].w);
        H1.x = hipack(pf[2].x, pf[2].y); H1.y = hipack(pf[2].z, pf[2].w);
        H1.z = hipack(pf[3].x, pf[3].y); H1.w = hipack(pf[3].z, pf[3].w);
        L0.x = lopack(pf[0].x, pf[0].y); L0.y = lopack(pf[0].z, pf[0].w);
        L0.z = lopack(pf[1].x, pf[1].y); L0.w = lopack(pf[1].z, pf[1].w);
        L1.x = lopack(pf[2].x, pf[2].y); L1.y = lopack(pf[2].z, pf[2].w);
        L1.z = lopack(pf[3].x, pf[3].y); L1.w = lopack(pf[3].z, pf[3].w);
        const int sm = srow & 15;
        *(uint4*)&stg[nb][half][srow][(fq * 2)         ^ sm][0] = H0;
        *(uint4*)&stg[nb][half][srow][(fq * 2 + 1)     ^ sm][0] = H1;
        *(uint4*)&stg[nb][half][srow][(8 + fq * 2)     ^ sm][0] = L0;
        *(uint4*)&stg[nb][half][srow][(8 + fq * 2 + 1) ^ sm][0] = L1;
    };

    // prologue: stage e0 into buf 0 (compiler inserts counted vmcnt for pf use);
    // issue e0+1 loads, then raw barrier (loads stay in flight across it).
    ld(e0);
    cw(0);
    ld(e0 + 1);
    asm volatile("s_waitcnt lgkmcnt(0)" ::: "memory");
    __builtin_amdgcn_sched_barrier(0);
    __builtin_amdgcn_s_barrier();
    __builtin_amdgcn_sched_barrier(0);

    float us[Pc];
    #pragma unroll
    for (int p = 0; p < Pc; ++p) us[p] = 0.f;

    const int Arow = sr * 16 + n16;
    const int Brow = sc * 16 + n16;
#define RD(hf, rowv, slot) (*(const short8*)&stg[cur][hf][rowv][(slot) ^ ((rowv) & 15)][0])

    for (int t = 0; t < EC; ++t) {
        const int cur = t & 1;

        // 6 split-MFMAs (hh + lh + hl; ll dropped, ~2^-16 rel)
        f32x4 acc = {0.f, 0.f, 0.f, 0.f};
        {
            short8 a0 = RD(0, Arow, kg);            // Ah0
            short8 b0 = RD(1, Brow, kg);            // Bh0
            acc = __builtin_amdgcn_mfma_f32_16x16x32_bf16(a0, b0, acc, 0, 0, 0);
            short8 a1 = RD(0, Arow, 8 + kg);        // Al0
            acc = __builtin_amdgcn_mfma_f32_16x16x32_bf16(a1, b0, acc, 0, 0, 0);
            short8 b1 = RD(1, Brow, 8 + kg);        // Bl0
            acc = __builtin_amdgcn_mfma_f32_16x16x32_bf16(a0, b1, acc, 0, 0, 0);
            a0 = RD(0, Arow, 4 + kg);               // Ah1
            b0 = RD(1, Brow, 4 + kg);               // Bh1
            acc = __builtin_amdgcn_mfma_f32_16x16x32_bf16(a0, b0, acc, 0, 0, 0);
            a1 = RD(0, Arow, 12 + kg);              // Al1
            acc = __builtin_amdgcn_mfma_f32_16x16x32_bf16(a1, b0, acc, 0, 0, 0);
            b1 = RD(1, Brow, 12 + kg);              // Bl1
            acc = __builtin_amdgcn_mfma_f32_16x16x32_bf16(a0, b1, acc, 0, 0, 0);
        }

        // staging cluster BEFORE the fold: convert+write next slice (compiler
        // emits counted vmcnt for pf), issue t+2 loads, raw barrier — the new
        // loads cross it in flight. Fold below then overlaps other waves' reads.
        if (t + 1 < EC) {
            cw((t + 1) & 1);
            if (t + 2 < EC) ld(e0 + t + 2);
            asm volatile("s_waitcnt lgkmcnt(0)" ::: "memory");
            __builtin_amdgcn_sched_barrier(0);
            __builtin_amdgcn_s_barrier();
            __builtin_amdgcn_sched_barrier(0);
        }

        // fold atn into pose accumulators (straight-line)
        const float musC = (float)(e0 + t) * MUC;
        #pragma unroll
        for (int reg = 0; reg < 4; ++reg) {
            const float av = acc[reg];
            #pragma unroll
            for (int p = 0; p < Pc; ++p) {
                const float tt = dsc[p][reg] - musC;
                us[p] = fmaf(av, __builtin_amdgcn_exp2f(-tt * tt), us[p]);
            }
        }
    }
#undef RD

    // butterfly over 64 lanes, then across the 4 waves
    #pragma unroll
    for (int p = 0; p < Pc; ++p) {
        float v = us[p];
        #pragma unroll
        for (int off = 32; off >= 1; off >>= 1)
            v += __shfl_xor(v, off, 64);
        us[p] = v;
    }
    if (lane == 0) {
        #pragma unroll
        for (int p = 0; p < Pc; ++p) wred[w][p] = us[p];
    }
    __syncthreads();
    if (tid < Pc) {
        float s = 0.f;
        #pragma unroll
        for (int k = 0; k < 4; ++k) s += wred[k][tid];
        partial[(size_t)bid * Pc + tid] = s;
    }
}

// reduce NBLKM block-partials x 8 poses -> 8 outputs
__global__ void ff_reduce(const float* __restrict__ partial, float* __restrict__ out)
{
    const int w    = threadIdx.x >> 6;
    const int lane = threadIdx.x & 63;
    float v = 0.f;
    #pragma unroll
    for (int j = 0; j < NBLKM / 64; ++j)
        v += partial[(size_t)(lane + 64 * j) * Pc + w];
    #pragma unroll
    for (int off = 32; off >= 1; off >>= 1)
        v += __shfl_xor(v, off, 64);
    if (lane == 0) out[w] = 0.1f * v;
}

extern "C" void kernel_launch(void* const* d_in, const int* in_sizes, int n_in,
                              void* d_out, int out_size, void* d_ws, size_t ws_size,
                              hipStream_t stream)
{
    const float* lig_feat   = (const float*)d_in[0];
    const float* rec_feat   = (const float*)d_in[1];
    const float* lig_coords = (const float*)d_in[2];
    const float* rec_coords = (const float*)d_in[3];
    float* out     = (float*)d_out;
    float* partial = (float*)d_ws;   // 1024*8*4 = 32 KB

    ff_mfma<<<NBLKM, 256, 0, stream>>>(lig_feat, rec_feat, lig_coords, rec_coords, partial);
    ff_reduce<<<1, 512, 0, stream>>>(partial, out);
}

// Round 22
// 32.090 us; speedup vs baseline: 2.9004x; 1.0634x over previous
//
#include <hip/hip_runtime.h>
#include <math.h>

#define Lc 128
#define Rc 1024
#define Pc 8
#define Ec 64
#define Fc 64

// exp(-((d-mu)/sigma)^2) = exp2(-(C*(d-mu))^2), C = (1/0.15625)*sqrt(log2(e))
#define CSCALE   7.68718341623328f
#define MU_STEP  0.15873015873015873f   // 10/63
#define MUC      (MU_STEP * CSCALE)

#define BM 32        // l per block
#define BN 32        // r per block
#define ECB 16       // e per block (two independent 8-e halves)
#define EH 8         // e per half
#define NBLKM ((Lc/BM) * (Rc/BN) * (Ec/ECB))   // 4*32*4 = 512

typedef __attribute__((ext_vector_type(8))) short short8;   // 8 bf16
typedef __attribute__((ext_vector_type(4))) float f32x4;

__device__ __forceinline__ unsigned short bf16_rn(float x) {
    unsigned int u = __float_as_uint(x);
    u += 0x7FFF + ((u >> 16) & 1);
    return (unsigned short)(u >> 16);
}
// pack hi-bf16 (TRUNCATED) of two f32
__device__ __forceinline__ unsigned int hipack(float x0, float x1) {
    return (__float_as_uint(x0) >> 16) | (__float_as_uint(x1) & 0xFFFF0000u);
}
// pack lo-bf16 (residual vs truncated hi) of two f32
__device__ __forceinline__ unsigned int lopack(float x0, float x1) {
    float r0 = x0 - __uint_as_float(__float_as_uint(x0) & 0xFFFF0000u);
    float r1 = x1 - __uint_as_float(__float_as_uint(x1) & 0xFFFF0000u);
    return ((unsigned int)bf16_rn(r1) << 16) | (unsigned int)bf16_rn(r0);
}

// ---- fused cvt+GEMM+fold, 8 waves = 2 e-halves x 4 subtile-waves ----
// Each 256-thread half owns a disjoint stg slice + 8-e range: R17's verified
// pipeline runs twice per block -> half the prologues chip-wide at equal TLP.
__global__ __launch_bounds__(512, 2)
void ff_mfma(const float* __restrict__ lig_feat,
             const float* __restrict__ rec_feat,
             const float* __restrict__ lig_coords,
             const float* __restrict__ rec_coords,
             float* __restrict__ partial)
{
    // [se][buf][A/B][row][slot][8 shorts] = 64 KB
    __shared__ __align__(16) unsigned short stg[2][2][2][32][16][8];
    __shared__ float lcs[Pc][96];
    __shared__ float rcs[96];
    __shared__ float wred[8][Pc];

    const int tid  = threadIdx.x;
    const int lane = tid & 63;
    const int w    = tid >> 6;          // 0..7
    const int se   = w >> 2;            // e-half
    const int wq   = w & 3;
    const int n16  = lane & 15;
    const int kg   = lane >> 4;
    const int sr   = wq >> 1;           // subtile row (l)
    const int sc   = wq & 1;            // subtile col (r)

    // grid decode; bid&7 = XCD: each XCD owns 4 rt (rec slice 2 MB, L2-resident)
    const int bid = blockIdx.x;
    const int loc = bid >> 3;                   // 0..63
    const int rt  = (bid & 7) * 4 + (loc & 3);  // 0..31
    const int lt  = (loc >> 2) & 3;             // 0..3
    const int ez  = loc >> 4;                   // 0..3
    const int r0  = rt * BN;
    const int l0  = lt * BM;
    const int eh  = ez * ECB + se * EH;         // this half's e-base

    // staging roles (within each 256-thread half): half=A/B, srow, f-quarter
    const int sgA  = (tid >> 7) & 1;            // A/B selector
    const int srow = (tid >> 2) & 31;
    const int fq   = tid & 3;
    const float* sbase = (sgA ? rec_feat + (size_t)(r0 + srow) * (Ec * Fc)
                              : lig_feat + (size_t)(l0 + srow) * (Ec * Fc)) + fq * 16;

    float4 pf[4];
    auto ld = [&](int e) {
        #pragma unroll
        for (int j = 0; j < 4; ++j)
            pf[j] = *(const float4*)(sbase + (size_t)e * Fc + j * 4);
    };
    auto cw = [&](int nb) {   // convert pf -> split bf16, write 4 swizzled slots
        uint4 H0, H1, L0, L1;
        H0.x = hipack(pf[0].x, pf[0].y); H0.y = hipack(pf[0].z, pf[0].w);
        H0.z = hipack(pf[1].x, pf[1].y); H0.w = hipack(pf[1].z, pf[1].w);
        H1.x = hipack(pf[2].x, pf[2].y); H1.y = hipack(pf[2].z, pf[2].w);
        H1.z = hipack(pf[3].x, pf[3].y); H1.w = hipack(pf[3].z, pf[3].w);
        L0.x = lopack(pf[0].x, pf[0].y); L0.y = lopack(pf[0].z, pf[0].w);
        L0.z = lopack(pf[1].x, pf[1].y); L0.w = lopack(pf[1].z, pf[1].w);
        L1.x = lopack(pf[2].x, pf[2].y); L1.y = lopack(pf[2].z, pf[2].w);
        L1.z = lopack(pf[3].x, pf[3].y); L1.w = lopack(pf[3].z, pf[3].w);
        const int sm = srow & 15;
        *(uint4*)&stg[se][nb][sgA][srow][(fq * 2)         ^ sm][0] = H0;
        *(uint4*)&stg[se][nb][sgA][srow][(fq * 2 + 1)     ^ sm][0] = H1;
        *(uint4*)&stg[se][nb][sgA][srow][(8 + fq * 2)     ^ sm][0] = L0;
        *(uint4*)&stg[se][nb][sgA][srow][(8 + fq * 2 + 1) ^ sm][0] = L1;
    };

    // issue first staging loads EARLY: latency hides under coords+dsc below
    ld(eh);

    // coords -> LDS
    for (int i = tid; i < Pc * 96; i += 512) {
        int p = i / 96, q = i - p * 96;
        lcs[p][q] = lig_coords[p * (Lc * 3) + l0 * 3 + q];
    }
    if (tid < 96) rcs[tid] = rec_coords[r0 * 3 + tid];
    __syncthreads();

    // per-lane distances: l = sr*16 + kg*4 + reg, r = sc*16 + n16
    float dsc[Pc][4];
    {
        const int rb = (sc * 16 + n16) * 3;
        const float rx = rcs[rb], ry = rcs[rb + 1], rz = rcs[rb + 2];
        #pragma unroll
        for (int reg = 0; reg < 4; ++reg) {
            const int lb = (sr * 16 + kg * 4 + reg) * 3;
            #pragma unroll
            for (int p = 0; p < Pc; ++p) {
                float dx = lcs[p][lb]     - rx;
                float dy = lcs[p][lb + 1] - ry;
                float dz = lcs[p][lb + 2] - rz;
                dsc[p][reg] = sqrtf(dx * dx + dy * dy + dz * dz) * CSCALE;
            }
        }
    }

    // stage e(h) into buf 0; issue e(h)+1 loads; raw barrier (loads fly across)
    cw(0);
    ld(eh + 1);
    asm volatile("s_waitcnt lgkmcnt(0)" ::: "memory");
    __builtin_amdgcn_sched_barrier(0);
    __builtin_amdgcn_s_barrier();
    __builtin_amdgcn_sched_barrier(0);

    float us[Pc];
    #pragma unroll
    for (int p = 0; p < Pc; ++p) us[p] = 0.f;

    const int Arow = sr * 16 + n16;
    const int Brow = sc * 16 + n16;
#define RD(hf, rowv, slot) (*(const short8*)&stg[se][cur][hf][rowv][(slot) ^ ((rowv) & 15)][0])

    for (int t = 0; t < EH; ++t) {
        const int cur = t & 1;

        // 6 split-MFMAs (hh + lh + hl; ll dropped, ~2^-16 rel)
        f32x4 acc = {0.f, 0.f, 0.f, 0.f};
        {
            short8 a0 = RD(0, Arow, kg);            // Ah0
            short8 b0 = RD(1, Brow, kg);            // Bh0
            acc = __builtin_amdgcn_mfma_f32_16x16x32_bf16(a0, b0, acc, 0, 0, 0);
            short8 a1 = RD(0, Arow, 8 + kg);        // Al0
            acc = __builtin_amdgcn_mfma_f32_16x16x32_bf16(a1, b0, acc, 0, 0, 0);
            short8 b1 = RD(1, Brow, 8 + kg);        // Bl0
            acc = __builtin_amdgcn_mfma_f32_16x16x32_bf16(a0, b1, acc, 0, 0, 0);
            a0 = RD(0, Arow, 4 + kg);               // Ah1
            b0 = RD(1, Brow, 4 + kg);               // Bh1
            acc = __builtin_amdgcn_mfma_f32_16x16x32_bf16(a0, b0, acc, 0, 0, 0);
            a1 = RD(0, Arow, 12 + kg);              // Al1
            acc = __builtin_amdgcn_mfma_f32_16x16x32_bf16(a1, b0, acc, 0, 0, 0);
            b1 = RD(1, Brow, 12 + kg);              // Bl1
            acc = __builtin_amdgcn_mfma_f32_16x16x32_bf16(a0, b1, acc, 0, 0, 0);
        }

        // staging cluster before the fold (counted vmcnt; loads cross barrier)
        if (t + 1 < EH) {
            cw((t + 1) & 1);
            if (t + 2 < EH) ld(eh + t + 2);
            asm volatile("s_waitcnt lgkmcnt(0)" ::: "memory");
            __builtin_amdgcn_sched_barrier(0);
            __builtin_amdgcn_s_barrier();
            __builtin_amdgcn_sched_barrier(0);
        }

        // fold atn into pose accumulators (straight-line)
        const float musC = (float)(eh + t) * MUC;
        #pragma unroll
        for (int reg = 0; reg < 4; ++reg) {
            const float av = acc[reg];
            #pragma unroll
            for (int p = 0; p < Pc; ++p) {
                const float tt = dsc[p][reg] - musC;
                us[p] = fmaf(av, __builtin_amdgcn_exp2f(-tt * tt), us[p]);
            }
        }
    }
#undef RD

    // butterfly over 64 lanes, then across the 8 waves
    #pragma unroll
    for (int p = 0; p < Pc; ++p) {
        float v = us[p];
        #pragma unroll
        for (int off = 32; off >= 1; off >>= 1)
            v += __shfl_xor(v, off, 64);
        us[p] = v;
    }
    if (lane == 0) {
        #pragma unroll
        for (int p = 0; p < Pc; ++p) wred[w][p] = us[p];
    }
    __syncthreads();
    if (tid < Pc) {
        float s = 0.f;
        #pragma unroll
        for (int k = 0; k < 8; ++k) s += wred[k][tid];
        partial[(size_t)tid * NBLKM + bid] = s;   // [p][bid]: coalesced reduce
    }
}

// reduce: partial[p][0..NBLKM) -> out[p]; coalesced (lane-contiguous) loads
__global__ void ff_reduce(const float* __restrict__ partial, float* __restrict__ out)
{
    const int w    = threadIdx.x >> 6;  // pose = wave id (8 waves)
    const int lane = threadIdx.x & 63;
    float v = 0.f;
    #pragma unroll
    for (int j = 0; j < NBLKM / 64; ++j)
        v += partial[(size_t)w * NBLKM + lane + 64 * j];
    #pragma unroll
    for (int off = 32; off >= 1; off >>= 1)
        v += __shfl_xor(v, off, 64);
    if (lane == 0) out[w] = 0.1f * v;
}

extern "C" void kernel_launch(void* const* d_in, const int* in_sizes, int n_in,
                              void* d_out, int out_size, void* d_ws, size_t ws_size,
                              hipStream_t stream)
{
    const float* lig_feat   = (const float*)d_in[0];
    const float* rec_feat   = (const float*)d_in[1];
    const float* lig_coords = (const float*)d_in[2];
    const float* rec_coords = (const float*)d_in[3];
    float* out     = (float*)d_out;
    float* partial = (float*)d_ws;   // 8*512*4 = 16 KB

    ff_mfma<<<NBLKM, 512, 0, stream>>>(lig_feat, rec_feat, lig_coords, rec_coords, partial);
    ff_reduce<<<1, 512, 0, stream>>>(partial, out);
}